// Round 4
// baseline (2871.998 us; speedup 1.0000x reference)
//
#include <hip/hip_runtime.h>

// Paired-block VRNN. Pair = (bid, bid^4) on XCDs x / x+4. Each pair owns 32
// batch rows. Gate GEMM (the big weight stream) is N-split across the pair:
// per-XCD weight hot set = 1.66MB (WG half) + 0.77MB (small) = 2.4MB -> L2
// resident across all 16 steps. Small layers are row-split (no extra syncs).
// Two pair exchanges per step via agent-scope atomics (LLC), parity
// double-buffered, monotonic flags. Cooperative launch for co-residency.

typedef __attribute__((ext_vector_type(8))) short short8;
typedef __attribute__((ext_vector_type(4))) float f32x4;
typedef unsigned long long u64;
typedef __attribute__((ext_vector_type(2))) unsigned long long u64x2;

#define Bt 4096
#define Td 16

// U layout (shorts): z@0, y_prev@64, h@320, s@832, y_cur@1344 ; stride 1608
#define US 1608
#define UZ 0
#define UY 64
#define UH 320
#define USs 832
#define UC 1344
#define TS 264
#define HZS 72

// weight ws offsets in short8 (16B) chunks
#define OFF_WGH  0          // 2 halves x 4 gates x NT16 x KT26
#define OFF_WPHH 212992     // 2 x 4 x NT16 x KT16
#define OFF_W1   344064     // NT16 KT16
#define OFF_W2   360448     // NT16 KT8
#define OFF_W3   368640
#define OFF_W4D  376832     // NT4 KT32  K=[s|y_cur|y_prev]
#define OFF_W4H  385024     // NT4 KT16
#define OFF_W7D  389120     // NT4 KT24  K=[s|y_prev]
#define OFF_W7H  395264
#define OFF_W5   399360     // NT4 KT2
#define OFF_W6   399872
#define OFF_W8   400384
#define OFF_W9   400896

// exchange area byte offsets (from ws base); slot = ((g*2+half)*2+par), 512 slots
#define XH_BYTE  6422528ULL
#define XC_BYTE  (XH_BYTE + 512ULL*16384)
#define XY_BYTE  (XC_BYTE + 512ULL*16384)
#define XZ_BYTE  (XY_BYTE + 512ULL*8192)
#define FL_BYTE  (XZ_BYTE + 512ULL*2048)

#define O1 16777216
#define O2 20971520
#define O3 25165824

__device__ inline short f2bf(float f) {
  unsigned u = __builtin_bit_cast(unsigned, f);
  unsigned r = (u + 0x7FFFu + ((u >> 16) & 1u)) >> 16;
  return (short)(unsigned short)r;
}
__device__ inline float sigm(float x) { return 1.f / (1.f + __expf(-x)); }
__device__ inline float tanhx(float x) { return 1.f - 2.f / (__expf(2.f * x) + 1.f); }
__device__ inline unsigned pack2(float a, float b) {
  return (unsigned)(unsigned short)f2bf(a) | ((unsigned)(unsigned short)f2bf(b) << 16);
}
__device__ inline f32x4 unpack4(unsigned u0, unsigned u1) {
  f32x4 r;
  r[0] = __builtin_bit_cast(float, u0 << 16);
  r[1] = __builtin_bit_cast(float, u0 & 0xffff0000u);
  r[2] = __builtin_bit_cast(float, u1 << 16);
  r[3] = __builtin_bit_cast(float, u1 & 0xffff0000u);
  return r;
}

#define MFMA(a, b, c) __builtin_amdgcn_mfma_f32_16x16x32_bf16((a), (b), (c), 0, 0, 0)

// f32 row-major [K][N] (up to 3 concatenated row-ranges) -> bf16 MFMA frag:
// dst[(nt*KT+kt)*64+lane][j] = W[kt*32+(lane>>4)*8+j][col0 + nt*16 + (lane&15)]
__global__ void conv_frag(const float* s0, int k0, const float* s1, int k1,
                          const float* s2, int k2, int N, int col0,
                          short8* dst, int KT, int total) {
  int idx = blockIdx.x * blockDim.x + threadIdx.x;
  if (idx >= total) return;
  int lane = idx & 63;
  int tt = idx >> 6;
  int kt = tt % KT;
  int nt = tt / KT;
  int c = col0 + nt * 16 + (lane & 15);
  int kb = kt * 32 + (lane >> 4) * 8;
  short8 v;
#pragma unroll
  for (int j = 0; j < 8; ++j) {
    int kc = kb + j;
    float f;
    if (kc < k0) f = s0[(size_t)kc * N + c];
    else if (kc < k0 + k1) f = s1[(size_t)(kc - k0) * N + c];
    else f = s2[(size_t)(kc - k0 - k1) * N + c];
    v[j] = f2bf(f);
  }
  dst[idx] = v;
}

__global__ void init_flags(int* f) { if (threadIdx.x < 512) f[threadIdx.x] = 0; }

struct Params {
  const float* h_i; const float* eps_inf; const float* eps_pri;
  const float* b_lstm;
  const float *b1, *b2, *b3, *b4, *b5, *b6, *b7, *b8, *b9;
  const short8 *WGH, *WPHH, *W1f, *W2f, *W3f, *W4D, *W4H, *W7D, *W7H,
               *W5f, *W6f, *W8f, *W9f;
  u64 *XH, *XC, *XY, *XZ;
  int* flags;
  float* out;
};

__global__ __launch_bounds__(1024, 1) void vrnn_kernel(Params p) {
  __shared__ short U[32 * US];
  __shared__ short T1[16 * TS];
  __shared__ short T2[16 * TS];

  const int tid = threadIdx.x;
  const int wv = tid >> 6;
  const int lane = tid & 63;
  const int lrow = lane >> 4;
  const int lcol = lane & 15;
  const int bid = blockIdx.x;
  const int xcd = bid & 7;
  const int half = xcd >> 2;             // XCDs 0-3 -> half 0, 4-7 -> half 1
  const int g = (xcd & 3) * 32 + (bid >> 3);
  const int rowbase = g * 32;
  const int ownrow0 = half * 16;
  const int fown = (g * 2 + half) * 2;
  const int fpar = (g * 2 + (1 - half)) * 2;

  // ---- stage h_i into U.h ----
  for (int i = tid; i < 32 * 512; i += 1024) {
    int r = i >> 9, c = i & 511;
    U[r * US + UH + c] = f2bf(p.h_i[(size_t)(rowbase + r) * 512 + c]);
  }
  __syncthreads();

  // ---- base = h_i @ WxH + b_lstm (per wave: 2 rowtiles x 4 gates, bf16-packed)
  unsigned base_pk[2][4][2];
  {
    const short8* Wb = p.WPHH + (size_t)(half * 4) * 16 * 16 * 64;
    f32x4 a2[2][4];
#pragma unroll
    for (int G = 0; G < 4; ++G) {
      float b = p.b_lstm[G * 512 + half * 256 + wv * 16 + lcol];
      a2[0][G] = (f32x4){b, b, b, b};
      a2[1][G] = (f32x4){b, b, b, b};
    }
    for (int kt = 0; kt < 16; ++kt) {
      short8 a0 = *(const short8*)&U[lcol * US + UH + kt * 32 + lrow * 8];
      short8 a1 = *(const short8*)&U[(16 + lcol) * US + UH + kt * 32 + lrow * 8];
#pragma unroll
      for (int G = 0; G < 4; ++G) {
        short8 w = Wb[(size_t)((G * 16 + wv) * 16 + kt) * 64 + lane];
        a2[0][G] = MFMA(a0, w, a2[0][G]);
        a2[1][G] = MFMA(a1, w, a2[1][G]);
      }
    }
#pragma unroll
    for (int rh = 0; rh < 2; ++rh)
#pragma unroll
      for (int G = 0; G < 4; ++G) {
        base_pk[rh][G][0] = pack2(a2[rh][G][0], a2[rh][G][1]);
        base_pk[rh][G][1] = pack2(a2[rh][G][2], a2[rh][G][3]);
      }
  }
  // ---- base47 (waves 0-7, own rowtile) ----
  f32x4 base47 = (f32x4){0.f, 0.f, 0.f, 0.f};
  if (wv < 8) {
    int net = wv >> 2, q = wv & 3;
    const short8* W = net ? p.W7H : p.W4H;
    const float* bb = net ? p.b7 : p.b4;
    float b = bb[q * 16 + lcol];
    base47 = (f32x4){b, b, b, b};
    for (int kt = 0; kt < 16; ++kt) {
      short8 a = *(const short8*)&U[(ownrow0 + lcol) * US + UH + kt * 32 + lrow * 8];
      short8 w = W[(q * 16 + kt) * 64 + lane];
      base47 = MFMA(a, w, base47);
    }
  }
  __syncthreads();
  // zero dynamic U region (cols 0..1600, all 32 rows)
  for (int i = tid; i < 6400; i += 1024) {
    int r = i / 200, c8 = i % 200;
    *(short8*)&U[r * US + c8 * 8] = (short8){0, 0, 0, 0, 0, 0, 0, 0};
  }
  f32x4 cst[2];
  cst[0] = (f32x4){0.f, 0.f, 0.f, 0.f};
  cst[1] = (f32x4){0.f, 0.f, 0.f, 0.f};
  __syncthreads();

  // ---- time loop ----
  for (int t = 0; t < Td; ++t) {
    const int par = t & 1;
    // P1: gates (N-half), depth-1 weight prefetch
    f32x4 acc[2][4];
#pragma unroll
    for (int rh = 0; rh < 2; ++rh)
#pragma unroll
      for (int G = 0; G < 4; ++G)
        acc[rh][G] = unpack4(base_pk[rh][G][0], base_pk[rh][G][1]);
    {
      const short8* Wg = p.WGH + (size_t)(half * 4) * 16 * 26 * 64;
      short8 w[4], wn[4];
#pragma unroll
      for (int G = 0; G < 4; ++G)
        w[G] = Wg[(size_t)((G * 16 + wv) * 26) * 64 + lane];
      for (int kt = 0; kt < 26; ++kt) {
        short8 a0 = *(const short8*)&U[lcol * US + kt * 32 + lrow * 8];
        short8 a1 = *(const short8*)&U[(16 + lcol) * US + kt * 32 + lrow * 8];
        if (kt < 25) {
#pragma unroll
          for (int G = 0; G < 4; ++G)
            wn[G] = Wg[(size_t)((G * 16 + wv) * 26 + kt + 1) * 64 + lane];
        }
#pragma unroll
        for (int G = 0; G < 4; ++G) {
          acc[0][G] = MFMA(a0, w[G], acc[0][G]);
          acc[1][G] = MFMA(a1, w[G], acc[1][G]);
        }
#pragma unroll
        for (int G = 0; G < 4; ++G) w[G] = wn[G];
      }
    }
    __syncthreads();

    // P2: LSTM pointwise (own cols, all 32 rows)
    {
      int hc = half * 256 + wv * 16 + lcol;
#pragma unroll
      for (int rh = 0; rh < 2; ++rh)
#pragma unroll
        for (int r = 0; r < 4; ++r) {
          float iv = sigm(acc[rh][0][r]);
          float fv = sigm(acc[rh][1][r]);
          float gv = tanhx(acc[rh][2][r]);
          float ov = sigm(acc[rh][3][r]);
          float cn = fv * cst[rh][r] + iv * gv;
          cst[rh][r] = cn;
          float hn = ov * tanhx(cn);
          int row = rh * 16 + lrow * 4 + r;
          U[row * US + UH + hc] = f2bf(hn);
          U[row * US + USs + hc] = f2bf(cn);
        }
    }
    __syncthreads();
    // E1 write: own h,c halves -> XH,XC (agent atomics)
    {
      u64* xh = p.XH + (size_t)((g * 2 + half) * 2 + par) * 2048;
      u64* xc = p.XC + (size_t)((g * 2 + half) * 2 + par) * 2048;
      int row = tid >> 5, c8 = tid & 31;
      short8 hv = *(const short8*)&U[row * US + UH + half * 256 + c8 * 8];
      short8 cv = *(const short8*)&U[row * US + USs + half * 256 + c8 * 8];
      u64x2 h2 = __builtin_bit_cast(u64x2, hv);
      u64x2 c2 = __builtin_bit_cast(u64x2, cv);
      __hip_atomic_store(&xh[tid * 2 + 0], h2[0], __ATOMIC_RELAXED, __HIP_MEMORY_SCOPE_AGENT);
      __hip_atomic_store(&xh[tid * 2 + 1], h2[1], __ATOMIC_RELAXED, __HIP_MEMORY_SCOPE_AGENT);
      __hip_atomic_store(&xc[tid * 2 + 0], c2[0], __ATOMIC_RELAXED, __HIP_MEMORY_SCOPE_AGENT);
      __hip_atomic_store(&xc[tid * 2 + 1], c2[1], __ATOMIC_RELAXED, __HIP_MEMORY_SCOPE_AGENT);
    }
    __syncthreads();
    if (tid == 0) {
      __hip_atomic_fetch_add(&p.flags[fown + 0], 1, __ATOMIC_RELEASE, __HIP_MEMORY_SCOPE_AGENT);
      while (__hip_atomic_load(&p.flags[fpar + 0], __ATOMIC_ACQUIRE, __HIP_MEMORY_SCOPE_AGENT) < t + 1)
        __builtin_amdgcn_s_sleep(1);
    }
    __syncthreads();
    // E1 read: partner h,c -> U
    {
      u64* xh = p.XH + (size_t)((g * 2 + (1 - half)) * 2 + par) * 2048;
      u64* xc = p.XC + (size_t)((g * 2 + (1 - half)) * 2 + par) * 2048;
      int row = tid >> 5, c8 = tid & 31;
      u64x2 h2, c2;
      h2[0] = __hip_atomic_load(&xh[tid * 2 + 0], __ATOMIC_RELAXED, __HIP_MEMORY_SCOPE_AGENT);
      h2[1] = __hip_atomic_load(&xh[tid * 2 + 1], __ATOMIC_RELAXED, __HIP_MEMORY_SCOPE_AGENT);
      c2[0] = __hip_atomic_load(&xc[tid * 2 + 0], __ATOMIC_RELAXED, __HIP_MEMORY_SCOPE_AGENT);
      c2[1] = __hip_atomic_load(&xc[tid * 2 + 1], __ATOMIC_RELAXED, __HIP_MEMORY_SCOPE_AGENT);
      *(short8*)&U[row * US + UH + (1 - half) * 256 + c8 * 8] = __builtin_bit_cast(short8, h2);
      *(short8*)&U[row * US + USs + (1 - half) * 256 + c8 * 8] = __builtin_bit_cast(short8, c2);
    }
    __syncthreads();

    // P3: y-MLP (row-split: own 16 rows, full N)
    {
      float b = p.b1[wv * 16 + lcol];
      f32x4 o = (f32x4){b, b, b, b};
      for (int kt = 0; kt < 16; ++kt) {
        short8 a = *(const short8*)&U[(ownrow0 + lcol) * US + UH + kt * 32 + lrow * 8];
        o = MFMA(a, p.W1f[(wv * 16 + kt) * 64 + lane], o);
      }
#pragma unroll
      for (int r = 0; r < 4; ++r)
        T1[(lrow * 4 + r) * TS + wv * 16 + lcol] = f2bf(fmaxf(o[r], 0.f));
    }
    __syncthreads();
    {
      float b = p.b2[wv * 16 + lcol];
      f32x4 o = (f32x4){b, b, b, b};
      for (int kt = 0; kt < 8; ++kt) {
        short8 a = *(const short8*)&T1[lcol * TS + kt * 32 + lrow * 8];
        o = MFMA(a, p.W2f[(wv * 8 + kt) * 64 + lane], o);
      }
#pragma unroll
      for (int r = 0; r < 4; ++r)
        T2[(lrow * 4 + r) * TS + wv * 16 + lcol] = f2bf(fmaxf(o[r], 0.f));
    }
    __syncthreads();
    {
      float b = p.b3[wv * 16 + lcol];
      f32x4 o = (f32x4){b, b, b, b};
      for (int kt = 0; kt < 8; ++kt) {
        short8 a = *(const short8*)&T2[lcol * TS + kt * 32 + lrow * 8];
        o = MFMA(a, p.W3f[(wv * 8 + kt) * 64 + lane], o);
      }
#pragma unroll
      for (int r = 0; r < 4; ++r) {
        int crow = lrow * 4 + r;
        float v = fmaxf(o[r], 0.f);
        U[(ownrow0 + crow) * US + UC + wv * 16 + lcol] = f2bf(v);
        p.out[(size_t)(rowbase + ownrow0 + crow) * 4096 + t * 256 + wv * 16 + lcol] = v;
      }
    }
    __syncthreads();

    // P4: h_z (waves 0-3 inf K=1024dyn; waves 4-7 pri K=768dyn), own rows
    if (wv < 8) {
      int net = wv >> 2, q = wv & 3;
      f32x4 hz = base47;
      if (net == 0) {
        for (int kt = 0; kt < 32; ++kt) {
          int kk = kt < 16 ? USs + 32 * kt : (kt < 24 ? UC + 32 * (kt - 16) : UY + 32 * (kt - 24));
          short8 a = *(const short8*)&U[(ownrow0 + lcol) * US + kk + lrow * 8];
          hz = MFMA(a, p.W4D[(q * 32 + kt) * 64 + lane], hz);
        }
#pragma unroll
        for (int r = 0; r < 4; ++r)
          T1[(lrow * 4 + r) * HZS + q * 16 + lcol] = f2bf(fmaxf(hz[r], 0.f));
      } else {
        for (int kt = 0; kt < 24; ++kt) {
          int kk = kt < 16 ? USs + 32 * kt : UY + 32 * (kt - 16);
          short8 a = *(const short8*)&U[(ownrow0 + lcol) * US + kk + lrow * 8];
          hz = MFMA(a, p.W7D[(q * 24 + kt) * 64 + lane], hz);
        }
#pragma unroll
        for (int r = 0; r < 4; ++r)
          T2[(lrow * 4 + r) * HZS + q * 16 + lcol] = f2bf(fmaxf(hz[r], 0.f));
      }
    }
    __syncthreads();

    // P5: heads + sampling (waves 0-7)
    if (wv < 8) {
      int net = wv >> 2, q = wv & 3;
      const short8* Wm = net ? p.W8f : p.W5f;
      const short8* Wl = net ? p.W9f : p.W6f;
      const float* bm = net ? p.b8 : p.b5;
      const float* bl = net ? p.b9 : p.b6;
      const short* HZ = net ? T2 : T1;
      float b0 = bm[q * 16 + lcol], b1v = bl[q * 16 + lcol];
      f32x4 om = (f32x4){b0, b0, b0, b0};
      f32x4 ol = (f32x4){b1v, b1v, b1v, b1v};
#pragma unroll
      for (int kt = 0; kt < 2; ++kt) {
        short8 a = *(const short8*)&HZ[lcol * HZS + kt * 32 + lrow * 8];
        om = MFMA(a, Wm[(q * 2 + kt) * 64 + lane], om);
        ol = MFMA(a, Wl[(q * 2 + kt) * 64 + lane], ol);
      }
      const float* eps = net ? p.eps_pri : p.eps_inf;
#pragma unroll
      for (int r = 0; r < 4; ++r) {
        int crow = lrow * 4 + r;
        int grow = rowbase + ownrow0 + crow;
        int col = q * 16 + lcol;
        float mv = fmaxf(om[r], 0.f), lv = fmaxf(ol[r], 0.f);
        float ev = eps[((size_t)t * Bt + grow) * 64 + col];
        float zv = mv + ev * sqrtf(__expf(lv));
        if (net == 0) {
          size_t gb = (size_t)grow * 1024 + t * 64 + col;
          p.out[O1 + gb] = mv;
          p.out[O2 + gb] = lv;
          p.out[O3 + ((size_t)(t * 2 + 0) * Bt + grow) * 64 + col] = zv;
          U[(ownrow0 + crow) * US + UZ + col] = f2bf(zv);
        } else {
          p.out[O3 + ((size_t)(t * 2 + 1) * Bt + grow) * 64 + col] = zv;
        }
      }
    }
    __syncthreads();
    // E2 write: own y (16x256) and z (16x64)
    {
      int slot = (g * 2 + half) * 2 + par;
      if (tid >= 512) {
        int i = tid - 512;
        int row = i >> 5, c8 = i & 31;
        short8 v = *(const short8*)&U[(ownrow0 + row) * US + UC + c8 * 8];
        u64x2 v2 = __builtin_bit_cast(u64x2, v);
        u64* xy = p.XY + (size_t)slot * 1024;
        __hip_atomic_store(&xy[i * 2 + 0], v2[0], __ATOMIC_RELAXED, __HIP_MEMORY_SCOPE_AGENT);
        __hip_atomic_store(&xy[i * 2 + 1], v2[1], __ATOMIC_RELAXED, __HIP_MEMORY_SCOPE_AGENT);
      } else if (tid < 128) {
        int row = tid >> 3, c8 = tid & 7;
        short8 v = *(const short8*)&U[(ownrow0 + row) * US + UZ + c8 * 8];
        u64x2 v2 = __builtin_bit_cast(u64x2, v);
        u64* xz = p.XZ + (size_t)slot * 256;
        __hip_atomic_store(&xz[tid * 2 + 0], v2[0], __ATOMIC_RELAXED, __HIP_MEMORY_SCOPE_AGENT);
        __hip_atomic_store(&xz[tid * 2 + 1], v2[1], __ATOMIC_RELAXED, __HIP_MEMORY_SCOPE_AGENT);
      }
    }
    __syncthreads();
    if (tid == 0) {
      __hip_atomic_fetch_add(&p.flags[fown + 1], 1, __ATOMIC_RELEASE, __HIP_MEMORY_SCOPE_AGENT);
      while (__hip_atomic_load(&p.flags[fpar + 1], __ATOMIC_ACQUIRE, __HIP_MEMORY_SCOPE_AGENT) < t + 1)
        __builtin_amdgcn_s_sleep(1);
    }
    __syncthreads();
    // E2 read: partner y,z -> U.y_prev/U.z ; own y_cur -> y_prev
    {
      int pslot = (g * 2 + (1 - half)) * 2 + par;
      int prow0 = (1 - half) * 16;
      u64* xy = p.XY + (size_t)pslot * 1024;
      u64* xz = p.XZ + (size_t)pslot * 256;
      if (tid < 512) {
        int row = tid >> 5, c8 = tid & 31;
        u64x2 v2;
        v2[0] = __hip_atomic_load(&xy[tid * 2 + 0], __ATOMIC_RELAXED, __HIP_MEMORY_SCOPE_AGENT);
        v2[1] = __hip_atomic_load(&xy[tid * 2 + 1], __ATOMIC_RELAXED, __HIP_MEMORY_SCOPE_AGENT);
        *(short8*)&U[(prow0 + row) * US + UY + c8 * 8] = __builtin_bit_cast(short8, v2);
      } else if (tid < 640) {
        int i = tid - 512;
        int row = i >> 3, c8 = i & 7;
        u64x2 v2;
        v2[0] = __hip_atomic_load(&xz[i * 2 + 0], __ATOMIC_RELAXED, __HIP_MEMORY_SCOPE_AGENT);
        v2[1] = __hip_atomic_load(&xz[i * 2 + 1], __ATOMIC_RELAXED, __HIP_MEMORY_SCOPE_AGENT);
        *(short8*)&U[(prow0 + row) * US + UZ + c8 * 8] = __builtin_bit_cast(short8, v2);
      } else {
        int i = tid - 640;  // own y_cur -> y_prev : 512 chunks by 384 threads
        for (; i < 512; i += 384) {
          int row = i >> 5, c8 = i & 31;
          short8 v = *(const short8*)&U[(ownrow0 + row) * US + UC + c8 * 8];
          *(short8*)&U[(ownrow0 + row) * US + UY + c8 * 8] = v;
        }
      }
    }
    __syncthreads();
  }
}

extern "C" void kernel_launch(void* const* d_in, const int* in_sizes, int n_in,
                              void* d_out, int out_size, void* d_ws, size_t ws_size,
                              hipStream_t stream) {
  const float* h_i     = (const float*)d_in[0];
  const float* eps_inf = (const float*)d_in[1];
  const float* eps_pri = (const float*)d_in[2];
  const float* Wx      = (const float*)d_in[3];
  const float* Wh      = (const float*)d_in[4];
  const float* b_lstm  = (const float*)d_in[5];
  const float* W1 = (const float*)d_in[6];  const float* b1 = (const float*)d_in[7];
  const float* W2 = (const float*)d_in[8];  const float* b2 = (const float*)d_in[9];
  const float* W3 = (const float*)d_in[10]; const float* b3 = (const float*)d_in[11];
  const float* W4 = (const float*)d_in[12]; const float* b4 = (const float*)d_in[13];
  const float* W5 = (const float*)d_in[14]; const float* b5 = (const float*)d_in[15];
  const float* W6 = (const float*)d_in[16]; const float* b6 = (const float*)d_in[17];
  const float* W7 = (const float*)d_in[18]; const float* b7 = (const float*)d_in[19];
  const float* W8 = (const float*)d_in[20]; const float* b8 = (const float*)d_in[21];
  const float* W9 = (const float*)d_in[22]; const float* b9 = (const float*)d_in[23];
  short8* ws = (short8*)d_ws;
  char* wsb = (char*)d_ws;
  const float* nil = nullptr;

  auto cv = [&](const float* s0, int k0, const float* s1, int k1,
                const float* s2, int k2, int N, int col0, int off, int KT, int NT) {
    int total = NT * KT * 64;
    conv_frag<<<(total + 255) / 256, 256, 0, stream>>>(s0, k0, s1, k1, s2, k2,
                                                       N, col0, ws + off, KT, total);
  };
  for (int half = 0; half < 2; ++half)
    for (int G = 0; G < 4; ++G) {
      int col0 = G * 512 + half * 256;
      cv(Wx, 64, Wx + 576 * 2048, 256, Wh, 512, 2048, col0,
         OFF_WGH + (half * 4 + G) * 16 * 26 * 64, 26, 16);
      cv(Wx + 64 * 2048, 512, nil, 0, nil, 0, 2048, col0,
         OFF_WPHH + (half * 4 + G) * 16 * 16 * 64, 16, 16);
    }
  cv(W1, 512, nil, 0, nil, 0, 256, 0, OFF_W1, 16, 16);
  cv(W2, 256, nil, 0, nil, 0, 256, 0, OFF_W2, 8, 16);
  cv(W3, 256, nil, 0, nil, 0, 256, 0, OFF_W3, 8, 16);
  cv(W4 + 512 * 64, 512, W4 + 1024 * 64, 256, W4 + 1280 * 64, 256, 64, 0, OFF_W4D, 32, 4);
  cv(W4, 512, nil, 0, nil, 0, 64, 0, OFF_W4H, 16, 4);
  cv(W7 + 512 * 64, 512, W7 + 1024 * 64, 256, nil, 0, 64, 0, OFF_W7D, 24, 4);
  cv(W7, 512, nil, 0, nil, 0, 64, 0, OFF_W7H, 16, 4);
  cv(W5, 64, nil, 0, nil, 0, 64, 0, OFF_W5, 2, 4);
  cv(W6, 64, nil, 0, nil, 0, 64, 0, OFF_W6, 2, 4);
  cv(W8, 64, nil, 0, nil, 0, 64, 0, OFF_W8, 2, 4);
  cv(W9, 64, nil, 0, nil, 0, 64, 0, OFF_W9, 2, 4);

  int* flags = (int*)(wsb + FL_BYTE);
  init_flags<<<1, 512, 0, stream>>>(flags);

  static Params P;
  P = Params{h_i, eps_inf, eps_pri, b_lstm,
             b1, b2, b3, b4, b5, b6, b7, b8, b9,
             ws + OFF_WGH, ws + OFF_WPHH, ws + OFF_W1, ws + OFF_W2, ws + OFF_W3,
             ws + OFF_W4D, ws + OFF_W4H, ws + OFF_W7D, ws + OFF_W7H,
             ws + OFF_W5, ws + OFF_W6, ws + OFF_W8, ws + OFF_W9,
             (u64*)(wsb + XH_BYTE), (u64*)(wsb + XC_BYTE),
             (u64*)(wsb + XY_BYTE), (u64*)(wsb + XZ_BYTE),
             flags, (float*)d_out};
  void* args[] = {&P};
  hipLaunchCooperativeKernel((void*)vrnn_kernel, dim3(256), dim3(1024), args, 0, stream);
}